// Round 13
// baseline (84.939 us; speedup 1.0000x reference)
//
#include <hip/hip_runtime.h>

#define NQ     12
#define DIM    4096
#define QDEPTH 8
#define T      512                     // 8 waves, 2 per SIMD; 8 amps/thread
#define NBLK   256

typedef _Float16 h2 __attribute__((ext_vector_type(2)));
union S4 { float4 f; h2 h[4]; };       // one 16B coef chunk: {rr_own, ii_own, rr_part, ii_part}
union HB { h2 h; unsigned u; int i; };

// bank swizzle: fold state bits 7-5 into addr bits 2-0 and bits 10-9 into 4-3.
// Hand-verified: every b32 state access in both layouts hits 2 lanes/bank (free).
__device__ __forceinline__ int SW(int i) {
    return i ^ ((i >> 5) & 7) ^ (((i >> 9) & 3) << 3);
}

template <int CTRL>
__device__ __forceinline__ int dpp_i(int x) {
    return __builtin_amdgcn_update_dpp(x, x, CTRL, 0xF, 0xF, false);
}
template <int CTRL>
__device__ __forceinline__ float dpp_mov(float x) {
    return __int_as_float(dpp_i<CTRL>(__float_as_int(x)));
}
__device__ __forceinline__ float swz_xor4f(float x) {
    return __int_as_float(__builtin_amdgcn_ds_swizzle(__float_as_int(x), 0x101F));
}

// wave-internal xor exchange of a packed amp — ALL DPP (VALU pipe only):
// KIND 0: xor1 (quad_perm)  1: xor2 (quad_perm)  3: xor8 (row_ror:8)
template <int KIND>
__device__ __forceinline__ h2 xlane(h2 x) {
    HB b; b.h = x;
    if constexpr (KIND == 0)      b.i = dpp_i<0xB1>(b.i);
    else if constexpr (KIND == 1) b.i = dpp_i<0x4E>(b.i);
    else                          b.i = dpp_i<0x128>(b.i);
    return b.h;
}

// packed complex helpers: for coef X=(xr,xi), rr={xr,xr}, ii={-xi,xi};
// X (x) a = rr*a + ii*swap(a)  -> v_pk_fma_f16 (swap folds to op_sel)
__device__ __forceinline__ h2 csw(h2 a) { return __builtin_shufflevector(a, a, 1, 0); }
__device__ __forceinline__ h2 cmul(h2 rr, h2 ii, h2 a) { return rr * a + ii * csw(a); }
__device__ __forceinline__ h2 cfma(h2 rr, h2 ii, h2 a, h2 acc) { return acc + rr * a + ii * csw(a); }

// in-register gate on amp-index bit m (m in {4,2,1}).
// S0 = {m00rr, m00ii, m01rr, m01ii}; S1 = {m11rr, m11ii, m10rr, m10ii}
__device__ __forceinline__ void reg_gate8(h2 a[8], const int m, const S4 S0, const S4 S1) {
#pragma unroll
    for (int c = 0; c < 8; ++c) {
        if (c & m) continue;
        const int c1 = c | m;
        const h2 a0 = a[c], a1 = a[c1];
        h2 n0 = cmul(S0.h[0], S0.h[1], a0); n0 = cfma(S0.h[2], S0.h[3], a1, n0);
        h2 n1 = cmul(S1.h[2], S1.h[3], a0); n1 = cfma(S1.h[0], S1.h[1], a1, n1);
        a[c] = n0; a[c1] = n1;
    }
}

// lane-bit gate: C = this lane side's {own_rr, own_ii, part_rr, part_ii}
template <int KIND>
__device__ __forceinline__ void lane_gate8(h2 a[8], const S4 C) {
#pragma unroll
    for (int c = 0; c < 8; ++c) {
        const h2 p = xlane<KIND>(a[c]);
        h2 n = cmul(C.h[0], C.h[1], a[c]);
        a[c] = cfma(C.h[2], C.h[3], p, n);
    }
}

// 9 coef chunks for one 6-gate group (3 reg gates: both sides; 3 lane: own side)
__device__ __forceinline__ void load_coefs9(const float4* __restrict__ m4,
                                            const int gi0, const int g3,
                                            const int g1, const int g0, S4 R[9]) {
    const float4* G = m4 + gi0 * 2;
    R[0].f = G[0]; R[1].f = G[1]; R[2].f = G[2];
    R[3].f = G[3]; R[4].f = G[4]; R[5].f = G[5];
    R[6].f = G[6  + g3];
    R[7].f = G[8  + g1];
    R[8].f = G[10 + g0];
}

// 6 gates: wires gb..gb+2 -> c bits 2,1,0 (reg); gb+3 -> xor8, gb+4 -> xor2,
// gb+5 -> xor1 (all DPP)
__device__ __forceinline__ void apply6(h2 a[8], const S4 R[9]) {
    reg_gate8(a, 4, R[0], R[1]);
    reg_gate8(a, 2, R[2], R[3]);
    reg_gate8(a, 1, R[4], R[5]);
    lane_gate8<3>(a, R[6]);
    lane_gate8<1>(a, R[7]);
    lane_gate8<0>(a, R[8]);
}

// CZ-product diagonal for layer d (range r=d+1): flip both halves' sign bits
__device__ __forceinline__ void apply_cz8(h2 a[8], const int ii[8], const int d) {
    const int r = d + 1;
#pragma unroll
    for (int c = 0; c < 8; ++c) {
        const unsigned i  = (unsigned)ii[c];
        const unsigned ro = ((i << r) | (i >> (12 - r))) & 0xFFFu;
        HB b; b.h = a[c];
        b.u ^= (__popc(i & ro) & 1) ? 0x80008000u : 0u;
        a[c] = b.h;
    }
}

// merged pass: coef prefetch -> barrier -> amp load -> gates(l1) -> CZ(l1) ->
// gates(l1+1) -> store
__device__ __forceinline__ void merged_pass(h2* __restrict__ st,
                                            const float4* __restrict__ m4,
                                            const int ja[8], const int ii[8],
                                            const int gbase, const int l1,
                                            const int g3, const int g1,
                                            const int g0, h2 a[8]) {
    S4 R1[9], R2[9];
    load_coefs9(m4, l1 * NQ + gbase, g3, g1, g0, R1);         // pre-barrier
    __syncthreads();
#pragma unroll
    for (int c = 0; c < 8; ++c) a[c] = st[ja[c]];
    load_coefs9(m4, (l1 + 1) * NQ + gbase, g3, g1, g0, R2);   // behind apply6(R1)
    apply6(a, R1);
    apply_cz8(a, ii, l1);
    apply6(a, R2);
#pragma unroll
    for (int c = 0; c < 8; ++c) st[ja[c]] = a[c];
}

// ---------------------------------------------------------------------------
// Fused kernel: every block redundantly simulates the 12-qubit circuit in
// packed fp16 (batch-independent: input encoding is a global phase), reduces
// <Z> in fp32, computes the row, writes its 1/256th of the broadcast output.
// ---------------------------------------------------------------------------
__global__ __launch_bounds__(T) void qnn_fused(const float* __restrict__ qw,
                                               const float* __restrict__ w_up,
                                               const float* __restrict__ b_up,
                                               float* __restrict__ out) {
    __shared__ h2     st[DIM];          // 16 KB state
    __shared__ float4 mats4[96 * 2];    // per gate: [side0][side1], 16B each
    __shared__ float  zred[T / 64][NQ];
    __shared__ float  zfin[NQ];
    __shared__ float4 row4[196];

    const int tid  = threadIdx.x;
    const int lane = tid & 63;
    const int g0 = lane & 1, g1 = (lane >> 1) & 1, g3 = (lane >> 3) & 1;
    const int s2 = (lane >> 2) & 1, s4 = (lane >> 4) & 1, s5 = (lane >> 5) & 1;
    const int w  = tid >> 6;           // wave id, 3 bits

    // prologue over 192 threads: thread (g,h) packs gate g side h
    if (tid < 192) {
        const int g = tid >> 1, hh = tid & 1;
        const float phi = qw[g * 3 + 0], theta = qw[g * 3 + 1], omega = qw[g * 3 + 2];
        float c, s, sp, cp, sm, cm;
        sincosf(0.5f * theta, &s, &c);
        sincosf(0.5f * (phi + omega), &sp, &cp);
        sincosf(0.5f * (phi - omega), &sm, &cm);
        // Rot = RZ(omega) RY(theta) RZ(phi):
        // m00=(cp*c,-sp*c) m01=(-cm*s,-sm*s) m10=(cm*s,-sm*s) m11=(cp*c,sp*c)
        S4 u;
        if (hh == 0) {   // side0: m00 | m01
            u.h[0] = (h2){(_Float16)(cp * c),  (_Float16)(cp * c)};
            u.h[1] = (h2){(_Float16)(sp * c),  (_Float16)(-sp * c)};  // {-m00i, m00i}
            u.h[2] = (h2){(_Float16)(-cm * s), (_Float16)(-cm * s)};
            u.h[3] = (h2){(_Float16)(sm * s),  (_Float16)(-sm * s)};  // {-m01i, m01i}
        } else {         // side1: m11 | m10
            u.h[0] = (h2){(_Float16)(cp * c),  (_Float16)(cp * c)};
            u.h[1] = (h2){(_Float16)(-sp * c), (_Float16)(sp * c)};   // {-m11i, m11i}
            u.h[2] = (h2){(_Float16)(cm * s),  (_Float16)(cm * s)};
            u.h[3] = (h2){(_Float16)(sm * s),  (_Float16)(-sm * s)};  // {-m10i, m10i}
        }
        mats4[g * 2 + hh] = u.f;
    }
    __syncthreads();

    // layout A (wires 0-5 in-thread): bits 11-9 = c, 8=g3, 7=g1, 6=g0,
    //   5=s5, 4=s4, 3=s2, 2-0 = wave.
    // layout B (wires 6-11 in-thread): bits 5-3 = c, 2=g3, 1=g1, 0=g0,
    //   11=s5, 10=s4, 9=s2, 8-6 = wave.
    int jaA[8], iiA[8], jaB[8], iiB[8];
#pragma unroll
    for (int c = 0; c < 8; ++c) {
        iiA[c] = (c << 9) | (g3 << 8) | (g1 << 7) | (g0 << 6)
               | (s5 << 5) | (s4 << 4) | (s2 << 3) | w;
        iiB[c] = (s5 << 11) | (s4 << 10) | (s2 << 9) | (w << 6)
               | (c << 3) | (g3 << 2) | (g1 << 1) | g0;
        jaA[c] = SW(iiA[c]);
        jaB[c] = SW(iiB[c]);
    }

    h2 a[8];
    // ---- P1 (layout B): analytic init replaces a full gate pass ----
    // After layer-0 wires 0-5 on |0..0>, amp[s] (bits5-0(s)==0) is the product
    // of first-column entries (m00 or m10) selected by bits 11-6 of s.
    {
        S4 R1[9], R2[9];
        load_coefs9(mats4, 0 * NQ + 6, g3, g1, g0, R1);
        load_coefs9(mats4, 1 * NQ + 6, g3, g1, g0, R2);
        const int h = iiB[0] >> 6;       // bits 11-6 (uniform across c)
        float pr = 1.f, pi = 0.f;
#pragma unroll
        for (int k = 0; k < 6; ++k) {
            const int b = (h >> (5 - k)) & 1;
            S4 u; u.f = mats4[k * 2 + b];
            const float cr = (float)(b ? u.h[2].x : u.h[0].x);   // m10r : m00r
            const float ci = (float)(b ? u.h[3].y : u.h[1].y);   // m10i : m00i
            const float nr = pr * cr - pi * ci;
            const float ni = pr * ci + pi * cr;
            pr = nr; pi = ni;
        }
        const bool nz = ((iiB[0] & 63) == 0);   // c==0 handled separately below
        a[0] = nz ? (h2){(_Float16)pr, (_Float16)pi} : (h2){(_Float16)0.f, (_Float16)0.f};
#pragma unroll
        for (int c = 1; c < 8; ++c) a[c] = (h2){(_Float16)0.f, (_Float16)0.f};
        apply6(a, R1);            // layer 0, wires 6-11
        apply_cz8(a, iiB, 0);     // CZ entangler, layer 0
        apply6(a, R2);            // layer 1, wires 6-11
#pragma unroll
        for (int c = 0; c < 8; ++c) st[jaB[c]] = a[c];
    }
    // ---- P2..P7: merged passes ----
    merged_pass(st, mats4, jaA, iiA, 0, 1, g3, g1, g0, a);   // L1 A, CZ1, L2 A
    merged_pass(st, mats4, jaB, iiB, 6, 2, g3, g1, g0, a);   // L2 B, CZ2, L3 B
    merged_pass(st, mats4, jaA, iiA, 0, 3, g3, g1, g0, a);   // L3 A, CZ3, L4 A
    merged_pass(st, mats4, jaB, iiB, 6, 4, g3, g1, g0, a);   // L4 B, CZ4, L5 B
    merged_pass(st, mats4, jaA, iiA, 0, 5, g3, g1, g0, a);   // L5 A, CZ5, L6 A
    merged_pass(st, mats4, jaB, iiB, 6, 6, g3, g1, g0, a);   // L6 B, CZ6, L7 B
    // ---- P8 (layout A): layer 7 wires 0-5; layer-7 CZ diag dropped ----
    {
        S4 R1[9];
        load_coefs9(mats4, 7 * NQ + 0, g3, g1, g0, R1);
        __syncthreads();
#pragma unroll
        for (int c = 0; c < 8; ++c) a[c] = st[jaA[c]];
        apply6(a, R1);
    }

    // per-thread Z partials, fp32 (amp indices iiA[c]: c bits 2,1,0 = wires 0,1,2)
    float p8[8];
#pragma unroll
    for (int c = 0; c < 8; ++c) {
        const float ar = (float)a[c].x, ai = (float)a[c].y;
        p8[c] = ar * ar + ai * ai;
    }
    const float t0 = p8[0] + p8[1], t1 = p8[2] + p8[3];
    const float t2 = p8[4] + p8[5], t3 = p8[6] + p8[7];
    const float e0 = p8[0] - p8[1], e1 = p8[2] - p8[3];
    const float e2 = p8[4] - p8[5], e3 = p8[6] - p8[7];
    const float S = (t0 + t1) + (t2 + t3);
    float zp[NQ];
    zp[0] = (t0 + t1) - (t2 + t3);     // wire 0 (c bit2)
    zp[1] = (t0 - t1) + (t2 - t3);     // wire 1 (c bit1)
    zp[2] = (e0 + e1) + (e2 + e3);     // wire 2 (c bit0)
#pragma unroll
    for (int w_ = 3; w_ < NQ; ++w_)
        zp[w_] = (((iiA[0] >> (11 - w_)) & 1) ? -S : S);

    // wave64 sum via xor butterfly over masks {1,2,4,8}, then 4 readlanes
#pragma unroll
    for (int w_ = 0; w_ < NQ; ++w_) {
        float v = zp[w_];
        v += dpp_mov<0xB1>(v);    // xor1
        v += dpp_mov<0x4E>(v);    // xor2
        v += swz_xor4f(v);        // xor4
        v += dpp_mov<0x128>(v);   // xor8
        const float r0 = __int_as_float(__builtin_amdgcn_readlane(__float_as_int(v), 0));
        const float r1 = __int_as_float(__builtin_amdgcn_readlane(__float_as_int(v), 16));
        const float r2 = __int_as_float(__builtin_amdgcn_readlane(__float_as_int(v), 32));
        const float r3 = __int_as_float(__builtin_amdgcn_readlane(__float_as_int(v), 48));
        zp[w_] = (r0 + r1) + (r2 + r3);
    }
    if (lane == 0) {
#pragma unroll
        for (int w_ = 0; w_ < NQ; ++w_) zred[w][w_] = zp[w_];
    }
    __syncthreads();
    if (tid < NQ) {
        float v = 0.0f;
#pragma unroll
        for (int k = 0; k < T / 64; ++k) v += zred[k][tid];
        zfin[tid] = v;
    }
    __syncthreads();

    // row[i] = b_up[i] + sum_j z[j] * w_up[i,j]   (fp32)
    for (int i = tid; i < 784; i += T) {
        float acc = b_up[i];
#pragma unroll
        for (int j = 0; j < NQ; ++j) acc += zfin[j] * w_up[i * NQ + j];
        ((float*)row4)[i] = acc;
    }
    __syncthreads();

    // broadcast: block writes 1568 consecutive float4 (256*1568 = 401408 =
    // 2048*784/4). 1568 = 8*196, so slot j maps to row4[j % 196]. Coalesced.
    const int base = blockIdx.x * 1568;
    for (int j = tid; j < 1568; j += T)
        ((float4*)out)[base + j] = row4[j % 196];
}

extern "C" void kernel_launch(void* const* d_in, const int* in_sizes, int n_in,
                              void* d_out, int out_size, void* d_ws, size_t ws_size,
                              hipStream_t stream) {
    // inputs: 0:x 1:w_down 2:b_down 3:w_up 4:b_up 5:qweights
    const float* w_up = (const float*)d_in[3];
    const float* b_up = (const float*)d_in[4];
    const float* qw   = (const float*)d_in[5];
    float* out = (float*)d_out;

    qnn_fused<<<NBLK, T, 0, stream>>>(qw, w_up, b_up, out);
}